// Round 11
// baseline (365.035 us; speedup 1.0000x reference)
//
#include <hip/hip_runtime.h>

#define N_NODES 50000
#define N_EDGES 1600000
#define IN_FEATS 128
#define N_HIDDEN 256
#define N_CLASSES 41
#define CHW 16                 // y1 chunk width (floats) = 64 B
#define NB_G 782               // ceil(50000/64)
#define ECAP 1024
#define NPB 16                 // nodes per block in agg0_mlp (3125 blocks)
#define IDEG_STRIDE 16         // pad each degree counter to its own 64 B

typedef short  bf16x8 __attribute__((ext_vector_type(8)));
typedef float  f32x4  __attribute__((ext_vector_type(4)));

// -------- workspace layout (bytes), 32.29 MB total (< 32.61 MB proven) --------
#define IDEG_OFF  0            // 50000*16 ints, padded (3.2 MB)
#define ROWS_OFF  3200000      // N_NODES+1 int
#define RANK_OFF  3404800      // rank 6.4 MB; y1 [3][N][16] f32 (9.6 MB) aliases this
#define ESRC_OFF  13004800     // N_EDGES int (6.4 MB)
#define FEATH_OFF 19404800     // N_NODES*IN_FEATS ushort (12.8 MB)
#define W1P_OFF   32204800     // 64 KB
#define W2P_OFF   32270336     // 24 KB

__device__ __forceinline__ unsigned short bf16rne(float x) {
    unsigned b = __float_as_uint(x);
    return (unsigned short)((b + 0x7FFFu + ((b >> 16) & 1u)) >> 16);
}
__device__ __forceinline__ float bf2f(unsigned short u) {
    return __uint_as_float((unsigned)u << 16);
}

// fused prep: [0,6250) deg+rank atomics | [6250,12500) feat->bf16
//             [12500,12628) pack W1     | [12628,12676) pack W2
#define NB_DEG  6250
#define NB_CONV 6250
__global__ void prep(const int* __restrict__ dst, int* __restrict__ ideg,
                     int* __restrict__ rank,
                     const float* __restrict__ feat, ushort* __restrict__ feat_h,
                     const float* __restrict__ W1, ushort* __restrict__ w1p,
                     const float* __restrict__ W2, ushort* __restrict__ w2p) {
    const int b = blockIdx.x, t = threadIdx.x;
    if (b < NB_DEG) {
        int e = b * 256 + t;
        rank[e] = atomicAdd(&ideg[dst[e] * IDEG_STRIDE], 1);
    } else if (b < NB_DEG + NB_CONV) {
        int p = (b - NB_DEG) * 256 + t;            // < 1,600,000 quads
        float4 v = ((const float4*)feat)[p];
        ushort4 o;
        o.x = bf16rne(v.x); o.y = bf16rne(v.y);
        o.z = bf16rne(v.z); o.w = bf16rne(v.w);
        ((ushort4*)feat_h)[p] = o;
    } else if (b < NB_DEG + NB_CONV + 128) {
        int idx = (b - NB_DEG - NB_CONV) * 256 + t;    // < 32768
        int j = idx & 7, l = (idx >> 3) & 63, ks = (idx >> 9) & 3, nt = idx >> 11;
        int k = ks * 32 + ((l >> 4) * 8) + j;
        int n = nt * 16 + (l & 15);
        w1p[idx] = bf16rne(W1[k * N_HIDDEN + n]);
    } else {
        int idx = (b - NB_DEG - NB_CONV - 128) * 256 + t;   // < 12288
        int j = idx & 7, l = (idx >> 3) & 63, ks = (idx >> 9) & 7, nt = idx >> 12;
        int k = ks * 32 + ((l >> 4) * 8) + j;
        int n = nt * 16 + (l & 15);
        w2p[idx] = (n < N_CLASSES) ? bf16rne(W2[k * N_CLASSES + n]) : (ushort)0;
    }
}

#define SCAN_THREADS 1024
#define SCAN_CHUNK ((N_NODES + SCAN_THREADS - 1) / SCAN_THREADS)   // 49
__global__ __launch_bounds__(SCAN_THREADS) void scan_kernel(
        const int* __restrict__ ideg, int* __restrict__ row_start) {
    __shared__ int part[SCAN_THREADS];
    int t = threadIdx.x;
    int lo = t * SCAN_CHUNK;
    int hi = min(lo + SCAN_CHUNK, N_NODES);
    int s = 0;
    for (int i = lo; i < hi; ++i) s += ideg[i * IDEG_STRIDE];
    part[t] = s;
    __syncthreads();
    for (int off = 1; off < SCAN_THREADS; off <<= 1) {
        int v = (t >= off) ? part[t - off] : 0;
        __syncthreads();
        if (t >= off) part[t] += v;
        __syncthreads();
    }
    int run = (t == 0) ? 0 : part[t - 1];
    for (int i = lo; i < hi; ++i) {
        row_start[i] = run;
        run += ideg[i * IDEG_STRIDE];
    }
    if (t == SCAN_THREADS - 1) row_start[N_NODES] = part[SCAN_THREADS - 1];
}

__global__ void fill2(const int* __restrict__ src, const int* __restrict__ dst,
                      const int* __restrict__ rank, const int* __restrict__ row_start,
                      int* __restrict__ edge_src) {
    int e = blockIdx.x * blockDim.x + threadIdx.x;
    if (e >= N_EDGES) return;
    edge_src[row_start[dst[e]] + rank[e]] = src[e];
}

// fused: gather 16 nodes (2/wave, bf16) -> GEMM1 MFMA -> relu -> GEMM2 MFMA
__global__ __launch_bounds__(512) void agg0_mlp(
        const ushort* __restrict__ feat_h, const int* __restrict__ row_start,
        const int* __restrict__ edge_src,
        const ushort* __restrict__ w1p, const float* __restrict__ b1,
        const ushort* __restrict__ w2p, float* __restrict__ y1) {
    __shared__ ushort xs[NPB][136];
    __shared__ ushort hs[NPB][264];
    const int t = threadIdx.x;
    const int w = t >> 6, lane = t & 63;
    const int half = lane >> 5, l31 = lane & 31;
    const int node0 = blockIdx.x * NPB;

    for (int i = 0; i < 2; ++i) {
        const int nl = w * 2 + i;
        const int node = node0 + nl;
        const int start = row_start[node];
        const int deg = row_start[node + 1] - start;
        float4 acc = make_float4(0.f, 0.f, 0.f, 0.f);
        for (int base = 0; base < deg; base += 64) {
            int cnt = deg - base; if (cnt > 64) cnt = 64;
            int myIdx = 0;
            if (lane < cnt) myIdx = edge_src[start + base + lane];
            for (int j = 0; j < cnt; j += 16) {
#pragma unroll
                for (int u = 0; u < 8; ++u) {
                    int e = j + 2 * u + half;
                    int sn = __shfl(myIdx, e);
                    if (e < cnt) {
                        ushort4 v = *(const ushort4*)(feat_h + ((size_t)sn << 7) + (l31 << 2));
                        acc.x += bf2f(v.x); acc.y += bf2f(v.y);
                        acc.z += bf2f(v.z); acc.w += bf2f(v.w);
                    }
                }
            }
        }
        acc.x += __shfl_xor(acc.x, 32);
        acc.y += __shfl_xor(acc.y, 32);
        acc.z += __shfl_xor(acc.z, 32);
        acc.w += __shfl_xor(acc.w, 32);
        if (half == 0) {
            float invd = 1.0f / fmaxf((float)deg, 1.0f);
            ushort4 sv;
            sv.x = bf16rne(acc.x * invd); sv.y = bf16rne(acc.y * invd);
            sv.z = bf16rne(acc.z * invd); sv.w = bf16rne(acc.w * invd);
            *(ushort4*)&xs[nl][l31 * 4] = sv;
        }
    }
    __syncthreads();

    bf16x8 afr[4];
#pragma unroll
    for (int ks = 0; ks < 4; ++ks)
        afr[ks] = *(const bf16x8*)&xs[lane & 15][ks * 32 + ((lane >> 4) * 8)];

    f32x4 c1[2] = {{0.f, 0.f, 0.f, 0.f}, {0.f, 0.f, 0.f, 0.f}};
#pragma unroll
    for (int nt = 0; nt < 2; ++nt) {
#pragma unroll
        for (int ks = 0; ks < 4; ++ks) {
            bf16x8 bfr = *(const bf16x8*)(w1p + (((w * 2 + nt) * 4 + ks) * 64 + lane) * 8);
            c1[nt] = __builtin_amdgcn_mfma_f32_16x16x32_bf16(afr[ks], bfr, c1[nt], 0, 0, 0);
        }
    }
#pragma unroll
    for (int nt = 0; nt < 2; ++nt) {
        float bb = b1[(w * 2 + nt) * 16 + (lane & 15)];
#pragma unroll
        for (int r = 0; r < 4; ++r) {
            float hv = fmaxf(c1[nt][r] + bb, 0.f);
            hs[(lane >> 4) * 4 + r][(w * 2 + nt) * 16 + (lane & 15)] = bf16rne(hv);
        }
    }
    __syncthreads();

    if (w < 3) {
        f32x4 c2 = {0.f, 0.f, 0.f, 0.f};
#pragma unroll
        for (int ks = 0; ks < 8; ++ks) {
            bf16x8 a2 = *(const bf16x8*)&hs[lane & 15][ks * 32 + ((lane >> 4) * 8)];
            bf16x8 b2f = *(const bf16x8*)(w2p + ((w * 8 + ks) * 64 + lane) * 8);
            c2 = __builtin_amdgcn_mfma_f32_16x16x32_bf16(a2, b2f, c2, 0, 0, 0);
        }
#pragma unroll
        for (int r = 0; r < 4; ++r) {
            int node = node0 + (lane >> 4) * 4 + r;
            y1[((size_t)w * N_NODES + node) * CHW + (lane & 15)] = c2[r];
        }
    }
}

// merged second aggregation: all 3 y1 chunks; 4-edge unroll (12 loads in flight)
__global__ __launch_bounds__(256) void gather1_all(
        const float* __restrict__ y1,
        const int* __restrict__ row_start, const int* __restrict__ edge_src,
        const float* __restrict__ b2, float* __restrict__ out) {
    __shared__ int eidx[4][ECAP];
    const int t = threadIdx.x;
    const int w = t >> 6, lane = t & 63;
    const int g = lane >> 2, l4 = lane & 3;
    const int n0w = blockIdx.x * 64 + w * 16;

    int v = row_start[min(n0w + lane, N_NODES)];
    const int gbase = __shfl(v, 0);
    const int sg = __shfl(v, g);
    const int cnt = __shfl(v, g + 1) - sg;
    const int sl = sg - gbase;
    const int tot = __shfl(v, 16) - gbase;

    for (int i = lane; i < min(tot, ECAP); i += 64)
        eidx[w][i] = edge_src[gbase + i];
    __syncthreads();

    int maxc = cnt;
#pragma unroll
    for (int off = 32; off; off >>= 1) maxc = max(maxc, __shfl_xor(maxc, off));

    const float* fp = y1 + l4 * 4;
    float4 r0 = make_float4(0.f,0.f,0.f,0.f);
    float4 r1 = make_float4(0.f,0.f,0.f,0.f);
    float4 r2 = make_float4(0.f,0.f,0.f,0.f);
    for (int k = 0; k < maxc; k += 4) {
        float4 v0[4], v1[4], v2[4];
        int nv = 0;
#pragma unroll
        for (int u = 0; u < 4; ++u) {
            int e = k + u;
            if (e < cnt) {
                int p = sl + e;
                int idx = (p < ECAP) ? eidx[w][p] : edge_src[gbase + p];
                v0[u] = *(const float4*)(fp + (size_t)idx * CHW);
                v1[u] = *(const float4*)(fp + ((size_t)N_NODES + idx) * CHW);
                v2[u] = *(const float4*)(fp + ((size_t)2 * N_NODES + idx) * CHW);
                nv = u + 1;
            }
        }
#pragma unroll
        for (int u = 0; u < 4; ++u) {
            if (u < nv) {
                r0.x += v0[u].x; r0.y += v0[u].y; r0.z += v0[u].z; r0.w += v0[u].w;
                r1.x += v1[u].x; r1.y += v1[u].y; r1.z += v1[u].z; r1.w += v1[u].w;
                r2.x += v2[u].x; r2.y += v2[u].y; r2.z += v2[u].z; r2.w += v2[u].w;
            }
        }
    }
    const int node = n0w + g;
    if (node < N_NODES) {
        float invd = 1.0f / fmaxf((float)cnt, 1.0f);
        float rr[3][4] = {{r0.x, r0.y, r0.z, r0.w},
                          {r1.x, r1.y, r1.z, r1.w},
                          {r2.x, r2.y, r2.z, r2.w}};
#pragma unroll
        for (int c = 0; c < 3; ++c) {
#pragma unroll
            for (int i = 0; i < 4; ++i) {
                int col = c * CHW + l4 * 4 + i;
                if (col < N_CLASSES)
                    out[(size_t)node * N_CLASSES + col] = rr[c][i] * invd + b2[col];
            }
        }
    }
}

extern "C" void kernel_launch(void* const* d_in, const int* in_sizes, int n_in,
                              void* d_out, int out_size, void* d_ws, size_t ws_size,
                              hipStream_t stream) {
    const float* feat = (const float*)d_in[0];
    const int*   src  = (const int*)d_in[1];
    const int*   dst  = (const int*)d_in[2];
    const float* W1   = (const float*)d_in[3];
    const float* b1   = (const float*)d_in[4];
    const float* W2   = (const float*)d_in[5];
    const float* b2   = (const float*)d_in[6];
    float* out = (float*)d_out;

    char* ws = (char*)d_ws;
    int*    ideg      = (int*)(ws + IDEG_OFF);
    int*    row_start = (int*)(ws + ROWS_OFF);
    int*    rank      = (int*)(ws + RANK_OFF);
    int*    edge_src  = (int*)(ws + ESRC_OFF);
    ushort* feat_h    = (ushort*)(ws + FEATH_OFF);
    ushort* w1p       = (ushort*)(ws + W1P_OFF);
    ushort* w2p       = (ushort*)(ws + W2P_OFF);
    float*  y1        = (float*)(ws + RANK_OFF);   // aliases rank (dead after fill2)

    hipMemsetAsync(ideg, 0, N_NODES * IDEG_STRIDE * 4, stream);
    prep<<<NB_DEG + NB_CONV + 128 + 48, 256, 0, stream>>>(
        dst, ideg, rank, feat, feat_h, W1, w1p, W2, w2p);
    scan_kernel<<<1, SCAN_THREADS, 0, stream>>>(ideg, row_start);
    fill2<<<(N_EDGES + 255) / 256, 256, 0, stream>>>(src, dst, rank, row_start, edge_src);

    agg0_mlp<<<N_NODES / NPB, 512, 0, stream>>>(feat_h, row_start, edge_src,
                                                w1p, b1, w2p, y1);

    gather1_all<<<NB_G, 256, 0, stream>>>(y1, row_start, edge_src, b2, out);
}

// Round 12
// 249.011 us; speedup vs baseline: 1.4659x; 1.4659x over previous
//
#include <hip/hip_runtime.h>

#define N_NODES 50000
#define N_EDGES 1600000
#define IN_FEATS 128
#define N_HIDDEN 256
#define N_CLASSES 41
#define CHW 16                 // y1 chunk width (floats) = 64 B
#define NB_G 782               // ceil(50000/64)
#define ECAP 1024
#define NPB 16                 // nodes per block in agg0_mlp (3125 blocks)
#define IDEG_STRIDE 16         // pad each degree counter to its own 64 B
#define SB 256                 // nodes per scan block
#define NSB ((N_NODES + SB - 1) / SB)   // 196

typedef short  bf16x8 __attribute__((ext_vector_type(8)));
typedef float  f32x4  __attribute__((ext_vector_type(4)));

// -------- workspace layout (bytes), < 32.61 MB proven --------
#define IDEG_OFF  0            // 50000*16 ints, padded (3.2 MB)
#define ROWS_OFF  3200000      // N_NODES+1 int
#define RANK_OFF  3404800      // rank 6.4 MB; y1 [3][N][16] f32 (9.6 MB) aliases this
#define ESRC_OFF  13004800     // N_EDGES int (6.4 MB)
#define FEATH_OFF 19404800     // N_NODES*IN_FEATS ushort (12.8 MB)
#define W1P_OFF   32204800     // 64 KB
#define W2P_OFF   32270336     // 24 KB
#define BSUM_OFF  32294912     // NSB ints (< 1 KB)

__device__ __forceinline__ unsigned short bf16rne(float x) {
    unsigned b = __float_as_uint(x);
    return (unsigned short)((b + 0x7FFFu + ((b >> 16) & 1u)) >> 16);
}
__device__ __forceinline__ float bf2f(unsigned short u) {
    return __uint_as_float((unsigned)u << 16);
}

// fused prep: [0,6250) deg+rank atomics | [6250,12500) feat->bf16
//             [12500,12628) pack W1     | [12628,12676) pack W2
#define NB_DEG  6250
#define NB_CONV 6250
__global__ void prep(const int* __restrict__ dst, int* __restrict__ ideg,
                     int* __restrict__ rank,
                     const float* __restrict__ feat, ushort* __restrict__ feat_h,
                     const float* __restrict__ W1, ushort* __restrict__ w1p,
                     const float* __restrict__ W2, ushort* __restrict__ w2p) {
    const int b = blockIdx.x, t = threadIdx.x;
    if (b < NB_DEG) {
        int e = b * 256 + t;
        rank[e] = atomicAdd(&ideg[dst[e] * IDEG_STRIDE], 1);
    } else if (b < NB_DEG + NB_CONV) {
        int p = (b - NB_DEG) * 256 + t;            // < 1,600,000 quads
        float4 v = ((const float4*)feat)[p];
        ushort4 o;
        o.x = bf16rne(v.x); o.y = bf16rne(v.y);
        o.z = bf16rne(v.z); o.w = bf16rne(v.w);
        ((ushort4*)feat_h)[p] = o;
    } else if (b < NB_DEG + NB_CONV + 128) {
        int idx = (b - NB_DEG - NB_CONV) * 256 + t;    // < 32768
        int j = idx & 7, l = (idx >> 3) & 63, ks = (idx >> 9) & 3, nt = idx >> 11;
        int k = ks * 32 + ((l >> 4) * 8) + j;
        int n = nt * 16 + (l & 15);
        w1p[idx] = bf16rne(W1[k * N_HIDDEN + n]);
    } else {
        int idx = (b - NB_DEG - NB_CONV - 128) * 256 + t;   // < 12288
        int j = idx & 7, l = (idx >> 3) & 63, ks = (idx >> 9) & 7, nt = idx >> 12;
        int k = ks * 32 + ((l >> 4) * 8) + j;
        int n = nt * 16 + (l & 15);
        w2p[idx] = (n < N_CLASSES) ? bf16rne(W2[k * N_CLASSES + n]) : (ushort)0;
    }
}

// hierarchical scan: a) per-block exclusive prefix + block sums
__global__ __launch_bounds__(SB) void scan_a(const int* __restrict__ ideg,
                                             int* __restrict__ row_start,
                                             int* __restrict__ bsum) {
    __shared__ int sh[SB];
    const int b = blockIdx.x, t = threadIdx.x;
    const int node = b * SB + t;
    int v = (node < N_NODES) ? ideg[node * IDEG_STRIDE] : 0;
    sh[t] = v;
    __syncthreads();
    for (int off = 1; off < SB; off <<= 1) {
        int x = (t >= off) ? sh[t - off] : 0;
        __syncthreads();
        sh[t] += x;
        __syncthreads();
    }
    if (node < N_NODES) row_start[node] = sh[t] - v;   // exclusive within block
    if (t == SB - 1) bsum[b] = sh[t];
}

// b) exclusive scan of block sums (NSB=196 <= 256), writes row_start[N]
__global__ __launch_bounds__(256) void scan_b(int* __restrict__ bsum,
                                              int* __restrict__ row_start) {
    __shared__ int sh[256];
    const int t = threadIdx.x;
    int v = (t < NSB) ? bsum[t] : 0;
    sh[t] = v;
    __syncthreads();
    for (int off = 1; off < 256; off <<= 1) {
        int x = (t >= off) ? sh[t - off] : 0;
        __syncthreads();
        sh[t] += x;
        __syncthreads();
    }
    if (t < NSB) bsum[t] = sh[t] - v;                  // exclusive
    if (t == NSB - 1) row_start[N_NODES] = sh[t];      // = N_EDGES
}

// c) add block offsets
__global__ __launch_bounds__(SB) void scan_c(const int* __restrict__ bsum,
                                             int* __restrict__ row_start) {
    const int node = blockIdx.x * SB + threadIdx.x;
    if (node < N_NODES) row_start[node] += bsum[blockIdx.x];
}

__global__ void fill2(const int* __restrict__ src, const int* __restrict__ dst,
                      const int* __restrict__ rank, const int* __restrict__ row_start,
                      int* __restrict__ edge_src) {
    int e = blockIdx.x * blockDim.x + threadIdx.x;
    if (e >= N_EDGES) return;
    edge_src[row_start[dst[e]] + rank[e]] = src[e];
}

// fused: gather 16 nodes (2/wave, bf16) -> GEMM1 MFMA -> relu -> GEMM2 MFMA
__global__ __launch_bounds__(512) void agg0_mlp(
        const ushort* __restrict__ feat_h, const int* __restrict__ row_start,
        const int* __restrict__ edge_src,
        const ushort* __restrict__ w1p, const float* __restrict__ b1,
        const ushort* __restrict__ w2p, float* __restrict__ y1) {
    __shared__ ushort xs[NPB][136];
    __shared__ ushort hs[NPB][264];
    const int t = threadIdx.x;
    const int w = t >> 6, lane = t & 63;
    const int half = lane >> 5, l31 = lane & 31;
    const int node0 = blockIdx.x * NPB;

    for (int i = 0; i < 2; ++i) {
        const int nl = w * 2 + i;
        const int node = node0 + nl;
        const int start = row_start[node];
        const int deg = row_start[node + 1] - start;
        float4 acc = make_float4(0.f, 0.f, 0.f, 0.f);
        for (int base = 0; base < deg; base += 64) {
            int cnt = deg - base; if (cnt > 64) cnt = 64;
            int myIdx = 0;
            if (lane < cnt) myIdx = edge_src[start + base + lane];
            for (int j = 0; j < cnt; j += 16) {
#pragma unroll
                for (int u = 0; u < 8; ++u) {
                    int e = j + 2 * u + half;
                    int sn = __shfl(myIdx, e);
                    if (e < cnt) {
                        ushort4 v = *(const ushort4*)(feat_h + ((size_t)sn << 7) + (l31 << 2));
                        acc.x += bf2f(v.x); acc.y += bf2f(v.y);
                        acc.z += bf2f(v.z); acc.w += bf2f(v.w);
                    }
                }
            }
        }
        acc.x += __shfl_xor(acc.x, 32);
        acc.y += __shfl_xor(acc.y, 32);
        acc.z += __shfl_xor(acc.z, 32);
        acc.w += __shfl_xor(acc.w, 32);
        if (half == 0) {
            float invd = 1.0f / fmaxf((float)deg, 1.0f);
            ushort4 sv;
            sv.x = bf16rne(acc.x * invd); sv.y = bf16rne(acc.y * invd);
            sv.z = bf16rne(acc.z * invd); sv.w = bf16rne(acc.w * invd);
            *(ushort4*)&xs[nl][l31 * 4] = sv;
        }
    }
    __syncthreads();

    bf16x8 afr[4];
#pragma unroll
    for (int ks = 0; ks < 4; ++ks)
        afr[ks] = *(const bf16x8*)&xs[lane & 15][ks * 32 + ((lane >> 4) * 8)];

    f32x4 c1[2] = {{0.f, 0.f, 0.f, 0.f}, {0.f, 0.f, 0.f, 0.f}};
#pragma unroll
    for (int nt = 0; nt < 2; ++nt) {
#pragma unroll
        for (int ks = 0; ks < 4; ++ks) {
            bf16x8 bfr = *(const bf16x8*)(w1p + (((w * 2 + nt) * 4 + ks) * 64 + lane) * 8);
            c1[nt] = __builtin_amdgcn_mfma_f32_16x16x32_bf16(afr[ks], bfr, c1[nt], 0, 0, 0);
        }
    }
#pragma unroll
    for (int nt = 0; nt < 2; ++nt) {
        float bb = b1[(w * 2 + nt) * 16 + (lane & 15)];
#pragma unroll
        for (int r = 0; r < 4; ++r) {
            float hv = fmaxf(c1[nt][r] + bb, 0.f);
            hs[(lane >> 4) * 4 + r][(w * 2 + nt) * 16 + (lane & 15)] = bf16rne(hv);
        }
    }
    __syncthreads();

    if (w < 3) {
        f32x4 c2 = {0.f, 0.f, 0.f, 0.f};
#pragma unroll
        for (int ks = 0; ks < 8; ++ks) {
            bf16x8 a2 = *(const bf16x8*)&hs[lane & 15][ks * 32 + ((lane >> 4) * 8)];
            bf16x8 b2f = *(const bf16x8*)(w2p + ((w * 8 + ks) * 64 + lane) * 8);
            c2 = __builtin_amdgcn_mfma_f32_16x16x32_bf16(a2, b2f, c2, 0, 0, 0);
        }
#pragma unroll
        for (int r = 0; r < 4; ++r) {
            int node = node0 + (lane >> 4) * 4 + r;
            y1[((size_t)w * N_NODES + node) * CHW + (lane & 15)] = c2[r];
        }
    }
}

// merged second aggregation: all 3 y1 chunks; 4-edge unroll (12 loads in flight)
__global__ __launch_bounds__(256) void gather1_all(
        const float* __restrict__ y1,
        const int* __restrict__ row_start, const int* __restrict__ edge_src,
        const float* __restrict__ b2, float* __restrict__ out) {
    __shared__ int eidx[4][ECAP];
    const int t = threadIdx.x;
    const int w = t >> 6, lane = t & 63;
    const int g = lane >> 2, l4 = lane & 3;
    const int n0w = blockIdx.x * 64 + w * 16;

    int v = row_start[min(n0w + lane, N_NODES)];
    const int gbase = __shfl(v, 0);
    const int sg = __shfl(v, g);
    const int cnt = __shfl(v, g + 1) - sg;
    const int sl = sg - gbase;
    const int tot = __shfl(v, 16) - gbase;

    for (int i = lane; i < min(tot, ECAP); i += 64)
        eidx[w][i] = edge_src[gbase + i];
    __syncthreads();

    int maxc = cnt;
#pragma unroll
    for (int off = 32; off; off >>= 1) maxc = max(maxc, __shfl_xor(maxc, off));

    const float* fp = y1 + l4 * 4;
    float4 r0 = make_float4(0.f,0.f,0.f,0.f);
    float4 r1 = make_float4(0.f,0.f,0.f,0.f);
    float4 r2 = make_float4(0.f,0.f,0.f,0.f);
    for (int k = 0; k < maxc; k += 4) {
        float4 v0[4], v1[4], v2[4];
        int nv = 0;
#pragma unroll
        for (int u = 0; u < 4; ++u) {
            int e = k + u;
            if (e < cnt) {
                int p = sl + e;
                int idx = (p < ECAP) ? eidx[w][p] : edge_src[gbase + p];
                v0[u] = *(const float4*)(fp + (size_t)idx * CHW);
                v1[u] = *(const float4*)(fp + ((size_t)N_NODES + idx) * CHW);
                v2[u] = *(const float4*)(fp + ((size_t)2 * N_NODES + idx) * CHW);
                nv = u + 1;
            }
        }
#pragma unroll
        for (int u = 0; u < 4; ++u) {
            if (u < nv) {
                r0.x += v0[u].x; r0.y += v0[u].y; r0.z += v0[u].z; r0.w += v0[u].w;
                r1.x += v1[u].x; r1.y += v1[u].y; r1.z += v1[u].z; r1.w += v1[u].w;
                r2.x += v2[u].x; r2.y += v2[u].y; r2.z += v2[u].z; r2.w += v2[u].w;
            }
        }
    }
    const int node = n0w + g;
    if (node < N_NODES) {
        float invd = 1.0f / fmaxf((float)cnt, 1.0f);
        float rr[3][4] = {{r0.x, r0.y, r0.z, r0.w},
                          {r1.x, r1.y, r1.z, r1.w},
                          {r2.x, r2.y, r2.z, r2.w}};
#pragma unroll
        for (int c = 0; c < 3; ++c) {
#pragma unroll
            for (int i = 0; i < 4; ++i) {
                int col = c * CHW + l4 * 4 + i;
                if (col < N_CLASSES)
                    out[(size_t)node * N_CLASSES + col] = rr[c][i] * invd + b2[col];
            }
        }
    }
}

extern "C" void kernel_launch(void* const* d_in, const int* in_sizes, int n_in,
                              void* d_out, int out_size, void* d_ws, size_t ws_size,
                              hipStream_t stream) {
    const float* feat = (const float*)d_in[0];
    const int*   src  = (const int*)d_in[1];
    const int*   dst  = (const int*)d_in[2];
    const float* W1   = (const float*)d_in[3];
    const float* b1   = (const float*)d_in[4];
    const float* W2   = (const float*)d_in[5];
    const float* b2   = (const float*)d_in[6];
    float* out = (float*)d_out;

    char* ws = (char*)d_ws;
    int*    ideg      = (int*)(ws + IDEG_OFF);
    int*    row_start = (int*)(ws + ROWS_OFF);
    int*    rank      = (int*)(ws + RANK_OFF);
    int*    edge_src  = (int*)(ws + ESRC_OFF);
    ushort* feat_h    = (ushort*)(ws + FEATH_OFF);
    ushort* w1p       = (ushort*)(ws + W1P_OFF);
    ushort* w2p       = (ushort*)(ws + W2P_OFF);
    int*    bsum      = (int*)(ws + BSUM_OFF);
    float*  y1        = (float*)(ws + RANK_OFF);   // aliases rank (dead after fill2)

    hipMemsetAsync(ideg, 0, N_NODES * IDEG_STRIDE * 4, stream);
    prep<<<NB_DEG + NB_CONV + 128 + 48, 256, 0, stream>>>(
        dst, ideg, rank, feat, feat_h, W1, w1p, W2, w2p);
    scan_a<<<NSB, SB, 0, stream>>>(ideg, row_start, bsum);
    scan_b<<<1, 256, 0, stream>>>(bsum, row_start);
    scan_c<<<NSB, SB, 0, stream>>>(bsum, row_start);
    fill2<<<(N_EDGES + 255) / 256, 256, 0, stream>>>(src, dst, rank, row_start, edge_src);

    agg0_mlp<<<N_NODES / NPB, 512, 0, stream>>>(feat_h, row_start, edge_src,
                                                w1p, b1, w2p, y1);

    gather1_all<<<NB_G, 256, 0, stream>>>(y1, row_start, edge_src, b2, out);
}